// Round 8
// baseline (61.304 us; speedup 1.0000x reference)
//
#include <hip/hip_runtime.h>

// Rips 1-skeleton Euler characteristic curve, B=4096 pts in [0,1]^3.
// bin t = min(ceil(d*31.5), 63); out[k] = 4096 - (#edges with bin <= k).
// All d <= sqrt(3) < t_max=2 => every pair is an edge, and t <= 55 (no clamp).
//
// SINGLE kernel (256 blocks x 512 thr) — R7's pair kernel with the reduce
// fused in to delete one graph node (R7 post-mortem: total time is harness
// poison fill 39.6us + ~5 nodes of launch overhead; kernels are ~5us).
// Block b owns rows {8b..8b+7} U {4088-8b..4095-8b} = exactly 32760 pairs.
// fp16 LDS points + packed-f16 math (verified: absmax 16384 << 1.7e5).
// Flush: device-scope atomic stores to DISTINCT addresses (coherent, no
// fence, no contention — R3's failure was same-address atomics + fences),
// then a release-stored per-block MAGIC flag. Flags need no init kernel:
// d_ws poison 0xAAAAAAAA != MAGIC. Last block (all 256 co-resident: 1/CU)
// spins on the flags, reduces partials with agent-scope loads, writes out.

#define B_PTS 4096
#define STEPS 64
#define NBLK 256
#define NTHR 512
#define NWAVES (NTHR / 64)   // 8
#define NCOPY 4
#define CSTRIDE 65           // copy c shifts LDS bank by c
#define MAGIC 0x13579BDF

typedef _Float16 half2_t __attribute__((ext_vector_type(2)));
typedef _Float16 half4_t __attribute__((ext_vector_type(4)));
typedef _Float16 half8_t __attribute__((ext_vector_type(8)));

__device__ __forceinline__ half2_t pk(float a, float b) {
    return __builtin_bit_cast(half2_t, __builtin_amdgcn_cvt_pkrtz(a, b));
}

__device__ __forceinline__ int bin_of(half2_t pxy, half2_t pzw,
                                      half2_t qxy, half2_t qzw) {
    const half2_t dxy = pxy - qxy;   // v_pk_add_f16
    const half2_t dzw = pzw - qzw;   // w components are 0 -> dzw.y = 0
#if __has_builtin(__builtin_amdgcn_fdot2)
    const float d2 = __builtin_amdgcn_fdot2(
        dxy, dxy, __builtin_amdgcn_fdot2(dzw, dzw, 0.0f, false), false);
#else
    const float dx = (float)dxy[0], dy = (float)dxy[1], dz = (float)dzw[0];
    const float d2 = fmaf(dz, dz, fmaf(dy, dy, dx * dx));
#endif
    const float d = __builtin_amdgcn_sqrtf(d2);
    // ceil(d*31.5) for d in [0, sqrt(3)]: trunc(d*31.5 + 1-eps), always <= 55.
    return (int)fmaf(d, 31.5f, 0.9999995f);
}

__global__ __launch_bounds__(NTHR) void rips_fused(
    const float* __restrict__ x, int* __restrict__ part,
    int* __restrict__ flag, float* __restrict__ out) {
    __shared__ half4_t pts[B_PTS];                 // 32 KB
    __shared__ int hist[NWAVES][NCOPY * CSTRIDE];  // 8.1 KB
    __shared__ int psum[8][STEPS];                 // 2 KB (finalizer only)
    __shared__ int cnt[STEPS];

    const int tid = threadIdx.x;
    const int wave = tid >> 6;
    const int b = blockIdx.x;

    // Stage: thread m packs points 8m..8m+7 (6 float4 loads -> 4 b128 LDS writes).
    {
        const float4* x4 = (const float4*)x;
        const int m = tid;
        const float4 f0 = x4[6 * m + 0], f1 = x4[6 * m + 1], f2 = x4[6 * m + 2];
        const float4 f3 = x4[6 * m + 3], f4 = x4[6 * m + 4], f5 = x4[6 * m + 5];
        union { half8_t v; half2_t h[4]; } u;
        u.h[0] = pk(f0.x, f0.y); u.h[1] = pk(f0.z, 0.f);
        u.h[2] = pk(f0.w, f1.x); u.h[3] = pk(f1.y, 0.f);
        *(half8_t*)&pts[8 * m + 0] = u.v;
        u.h[0] = pk(f1.z, f1.w); u.h[1] = pk(f2.x, 0.f);
        u.h[2] = pk(f2.y, f2.z); u.h[3] = pk(f2.w, 0.f);
        *(half8_t*)&pts[8 * m + 2] = u.v;
        u.h[0] = pk(f3.x, f3.y); u.h[1] = pk(f3.z, 0.f);
        u.h[2] = pk(f3.w, f4.x); u.h[3] = pk(f4.y, 0.f);
        *(half8_t*)&pts[8 * m + 4] = u.v;
        u.h[0] = pk(f4.z, f4.w); u.h[1] = pk(f5.x, 0.f);
        u.h[2] = pk(f5.y, f5.z); u.h[3] = pk(f5.w, 0.f);
        *(half8_t*)&pts[8 * m + 6] = u.v;
    }
    for (int k = tid; k < NWAVES * NCOPY * CSTRIDE; k += NTHR) (&hist[0][0])[k] = 0;
    __syncthreads();

    // Per-lane rotated histogram-copy pointers.
    int* hc[NCOPY];
#pragma unroll
    for (int c = 0; c < NCOPY; ++c) hc[c] = &hist[wave][((c + tid) & 3) * CSTRIDE];

    const int tb = 8 * b;             // top rows tb..tb+7
    const int bb = B_PTS - 8 - 8 * b; // bottom rows bb..bb+7

    // 56 intra-group pairs: wave 0 -> top, wave 1 -> bottom (28 each).
    if (tid < 128) {
        const int k = tid & 63;
        const int r = k >> 3, s = k & 7;
        if (r < s) {
            const int base = (tid < 64) ? tb : bb;
            const half4_t a = pts[base + r], c = pts[base + s];
            const int t = bin_of(__builtin_shufflevector(a, a, 0, 1),
                                 __builtin_shufflevector(a, a, 2, 3),
                                 __builtin_shufflevector(c, c, 0, 1),
                                 __builtin_shufflevector(c, c, 2, 3));
            atomicAdd(&hc[0][t], 1);
        }
    }

    // Main loops: 8 rows per group, predicate-free, 8 pairs per ds_read_b64.
#pragma unroll
    for (int grp = 0; grp < 2; ++grp) {
        const int i0 = grp ? bb : tb;
        half2_t Rxy[8], Rzw[8];
#pragma unroll
        for (int r = 0; r < 8; ++r) {
            const half4_t p = pts[i0 + r];  // wave-uniform -> LDS broadcast
            Rxy[r] = __builtin_shufflevector(p, p, 0, 1);
            Rzw[r] = __builtin_shufflevector(p, p, 2, 3);
        }
        for (int j = i0 + 8 + tid; j < B_PTS; j += NTHR) {
            const half4_t q = pts[j];
            const half2_t qxy = __builtin_shufflevector(q, q, 0, 1);
            const half2_t qzw = __builtin_shufflevector(q, q, 2, 3);
#pragma unroll
            for (int r = 0; r < 8; ++r) {
                const int t = bin_of(Rxy[r], Rzw[r], qxy, qzw);
                atomicAdd(&hc[r & 3][t], 1);
            }
        }
    }
    __syncthreads();

    // Flush: 64 device-scope atomic stores to distinct addresses (coherent,
    // no L1 caching, no contention), then release-store the block's flag.
    if (tid < STEPS) {
        int s = 0;
#pragma unroll
        for (int w = 0; w < NWAVES; ++w)
#pragma unroll
            for (int c = 0; c < NCOPY; ++c) s += hist[w][c * CSTRIDE + tid];
        __hip_atomic_store(&part[b * STEPS + tid], s,
                           __ATOMIC_RELAXED, __HIP_MEMORY_SCOPE_AGENT);
    }
    __syncthreads();  // all flush stores issued & drained before the flag
    if (tid == 0)
        __hip_atomic_store(&flag[b], MAGIC,
                           __ATOMIC_RELEASE, __HIP_MEMORY_SCOPE_AGENT);

    // Finalizer: last block waits for all flags, reduces, cumsums, writes.
    if (b == NBLK - 1) {
        if (tid < NBLK) {
            while (__hip_atomic_load(&flag[tid], __ATOMIC_ACQUIRE,
                                     __HIP_MEMORY_SCOPE_AGENT) != MAGIC)
                __builtin_amdgcn_s_sleep(8);
        }
        __syncthreads();

        const int bin = tid & 63, q = tid >> 6;       // 8 groups of 32 blocks
        int s = 0;
#pragma unroll 8
        for (int i = 0; i < NBLK / 8; ++i)
            s += __hip_atomic_load(&part[(q * (NBLK / 8) + i) * STEPS + bin],
                                   __ATOMIC_RELAXED, __HIP_MEMORY_SCOPE_AGENT);
        psum[q][bin] = s;
        __syncthreads();

        if (tid < STEPS) {
            int tot = 0;
#pragma unroll
            for (int w = 0; w < 8; ++w) tot += psum[w][tid];
            cnt[tid] = tot;
        }
        __syncthreads();
        if (tid == 0) {
            int acc = 0;
            for (int k = 0; k < STEPS; ++k) { acc += cnt[k]; cnt[k] = acc; }
        }
        __syncthreads();
        if (tid < STEPS) out[tid] = (float)B_PTS - (float)cnt[tid];
    }
}

extern "C" void kernel_launch(void* const* d_in, const int* in_sizes, int n_in,
                              void* d_out, int out_size, void* d_ws, size_t ws_size,
                              hipStream_t stream) {
    const float* x = (const float*)d_in[0];
    float* out = (float*)d_out;
    int* part = (int*)d_ws;            // NBLK*64 ints = 64 KB
    int* flag = part + NBLK * STEPS;   // NBLK ints; poison 0xAAAAAAAA != MAGIC

    rips_fused<<<NBLK, NTHR, 0, stream>>>(x, part, flag, out);
}

// Round 9
// 60.185 us; speedup vs baseline: 1.0186x; 1.0186x over previous
//
#include <hip/hip_runtime.h>

// Rips 1-skeleton Euler characteristic curve, B=4096 pts in [0,1]^3.
// bin t = min(ceil(d*31.5), 63); out[k] = 4096 - (#edges with bin <= k).
// All d <= sqrt(3) < t_max=2 => every pair is an edge, and t <= 55 (no clamp).
//
// FINAL (best-measured config, R7 = 60.28 us): two kernels.
// Session accounting: 39.6 us harness d_ws 0xAA poison (256 MiB fill at 85%
// HBM peak) + ~2-3 us d_in restore/d_out poison + ~8-10 us graph-node gaps
// + ~5 us kernels. R7 (2x less VALU/pair) and R8 (fused single dispatch)
// both moved <=1 us => the window is harness-floor dominated.
//
// K1 (256 blocks x 512 thr): all points in LDS as half4 {x,y,z,0} (fp16 safe:
// absmax 16384 << threshold 1.7e5). Block b owns rows {8b..8b+7} U
// {4088-8b..4095-8b} = exactly 32760 pairs. Per-pair: v_pk_add_f16 x2 +
// v_dot2_f32_f16 x2 + sqrt + fma + cvt. One ds_read_b64 feeds 8 pairs.
// Per-wave 4-copy bank-shifted LDS histograms, per-lane copy rotation.
// Flush = one coalesced 256 B plain store per block (no device atomics —
// R3 showed same-address atomic flush + fences cost 40+ us).
// K2: 1 block x 1024 thr reduces 256x64 partials, cumsum, write.

#define B_PTS 4096
#define STEPS 64
#define NBLK 256
#define NTHR 512
#define NWAVES (NTHR / 64)   // 8
#define NCOPY 4
#define CSTRIDE 65           // copy c shifts LDS bank by c

typedef _Float16 half2_t __attribute__((ext_vector_type(2)));
typedef _Float16 half4_t __attribute__((ext_vector_type(4)));
typedef _Float16 half8_t __attribute__((ext_vector_type(8)));

__device__ __forceinline__ half2_t pk(float a, float b) {
    return __builtin_bit_cast(half2_t, __builtin_amdgcn_cvt_pkrtz(a, b));
}

__device__ __forceinline__ int bin_of(half2_t pxy, half2_t pzw,
                                      half2_t qxy, half2_t qzw) {
    const half2_t dxy = pxy - qxy;   // v_pk_add_f16
    const half2_t dzw = pzw - qzw;   // w components are 0 -> dzw.y = 0
#if __has_builtin(__builtin_amdgcn_fdot2)
    const float d2 = __builtin_amdgcn_fdot2(
        dxy, dxy, __builtin_amdgcn_fdot2(dzw, dzw, 0.0f, false), false);
#else
    const float dx = (float)dxy[0], dy = (float)dxy[1], dz = (float)dzw[0];
    const float d2 = fmaf(dz, dz, fmaf(dy, dy, dx * dx));
#endif
    const float d = __builtin_amdgcn_sqrtf(d2);
    // ceil(d*31.5) for d in [0, sqrt(3)]: trunc(d*31.5 + 1-eps), always <= 55.
    return (int)fmaf(d, 31.5f, 0.9999995f);
}

__global__ __launch_bounds__(NTHR) void rips_pair(
    const float* __restrict__ x, int* __restrict__ part) {
    __shared__ half4_t pts[B_PTS];                 // 32 KB
    __shared__ int hist[NWAVES][NCOPY * CSTRIDE];  // 8.1 KB

    const int tid = threadIdx.x;
    const int wave = tid >> 6;
    const int b = blockIdx.x;

    // Stage: thread m packs points 8m..8m+7 (6 float4 loads -> 4 b128 LDS writes).
    {
        const float4* x4 = (const float4*)x;
        const int m = tid;
        const float4 f0 = x4[6 * m + 0], f1 = x4[6 * m + 1], f2 = x4[6 * m + 2];
        const float4 f3 = x4[6 * m + 3], f4 = x4[6 * m + 4], f5 = x4[6 * m + 5];
        union { half8_t v; half2_t h[4]; } u;
        u.h[0] = pk(f0.x, f0.y); u.h[1] = pk(f0.z, 0.f);
        u.h[2] = pk(f0.w, f1.x); u.h[3] = pk(f1.y, 0.f);
        *(half8_t*)&pts[8 * m + 0] = u.v;
        u.h[0] = pk(f1.z, f1.w); u.h[1] = pk(f2.x, 0.f);
        u.h[2] = pk(f2.y, f2.z); u.h[3] = pk(f2.w, 0.f);
        *(half8_t*)&pts[8 * m + 2] = u.v;
        u.h[0] = pk(f3.x, f3.y); u.h[1] = pk(f3.z, 0.f);
        u.h[2] = pk(f3.w, f4.x); u.h[3] = pk(f4.y, 0.f);
        *(half8_t*)&pts[8 * m + 4] = u.v;
        u.h[0] = pk(f4.z, f4.w); u.h[1] = pk(f5.x, 0.f);
        u.h[2] = pk(f5.y, f5.z); u.h[3] = pk(f5.w, 0.f);
        *(half8_t*)&pts[8 * m + 6] = u.v;
    }
    for (int k = tid; k < NWAVES * NCOPY * CSTRIDE; k += NTHR) (&hist[0][0])[k] = 0;
    __syncthreads();

    // Per-lane rotated histogram-copy pointers.
    int* hc[NCOPY];
#pragma unroll
    for (int c = 0; c < NCOPY; ++c) hc[c] = &hist[wave][((c + tid) & 3) * CSTRIDE];

    const int tb = 8 * b;             // top rows tb..tb+7
    const int bb = B_PTS - 8 - 8 * b; // bottom rows bb..bb+7

    // 56 intra-group pairs: wave 0 -> top, wave 1 -> bottom (28 each).
    if (tid < 128) {
        const int k = tid & 63;
        const int r = k >> 3, s = k & 7;
        if (r < s) {
            const int base = (tid < 64) ? tb : bb;
            const half4_t a = pts[base + r], c = pts[base + s];
            const int t = bin_of(__builtin_shufflevector(a, a, 0, 1),
                                 __builtin_shufflevector(a, a, 2, 3),
                                 __builtin_shufflevector(c, c, 0, 1),
                                 __builtin_shufflevector(c, c, 2, 3));
            atomicAdd(&hc[0][t], 1);
        }
    }

    // Main loops: 8 rows per group, predicate-free, 8 pairs per ds_read_b64.
#pragma unroll
    for (int grp = 0; grp < 2; ++grp) {
        const int i0 = grp ? bb : tb;
        half2_t Rxy[8], Rzw[8];
#pragma unroll
        for (int r = 0; r < 8; ++r) {
            const half4_t p = pts[i0 + r];  // wave-uniform -> LDS broadcast
            Rxy[r] = __builtin_shufflevector(p, p, 0, 1);
            Rzw[r] = __builtin_shufflevector(p, p, 2, 3);
        }
        for (int j = i0 + 8 + tid; j < B_PTS; j += NTHR) {
            const half4_t q = pts[j];
            const half2_t qxy = __builtin_shufflevector(q, q, 0, 1);
            const half2_t qzw = __builtin_shufflevector(q, q, 2, 3);
#pragma unroll
            for (int r = 0; r < 8; ++r) {
                const int t = bin_of(Rxy[r], Rzw[r], qxy, qzw);
                atomicAdd(&hc[r & 3][t], 1);
            }
        }
    }
    __syncthreads();

    // Flush: one coalesced 256 B plain store per block.
    if (tid < STEPS) {
        int s = 0;
#pragma unroll
        for (int w = 0; w < NWAVES; ++w)
#pragma unroll
            for (int c = 0; c < NCOPY; ++c) s += hist[w][c * CSTRIDE + tid];
        part[b * STEPS + tid] = s;
    }
}

#define RTHR 1024
#define RWAVES (RTHR / 64)  // 16

__global__ __launch_bounds__(RTHR) void rips_reduce(
    const int* __restrict__ part, float* __restrict__ out) {
    __shared__ int psum[RWAVES][STEPS];
    __shared__ int cnt[STEPS];
    const int t = threadIdx.x;
    const int bin = t & 63, q = t >> 6;

    const int per = NBLK / RWAVES;  // 16 blocks per wave
    const int* p = part + q * per * STEPS + bin;
    int s = 0;
#pragma unroll
    for (int i = 0; i < per; ++i) s += p[i * STEPS];
    psum[q][bin] = s;
    __syncthreads();

    if (t < STEPS) {
        int tot = 0;
#pragma unroll
        for (int w = 0; w < RWAVES; ++w) tot += psum[w][t];
        cnt[t] = tot;
    }
    __syncthreads();
    if (t == 0) {
        int acc = 0;
        for (int k = 0; k < STEPS; ++k) { acc += cnt[k]; cnt[k] = acc; }
    }
    __syncthreads();
    if (t < STEPS) out[t] = (float)B_PTS - (float)cnt[t];
}

extern "C" void kernel_launch(void* const* d_in, const int* in_sizes, int n_in,
                              void* d_out, int out_size, void* d_ws, size_t ws_size,
                              hipStream_t stream) {
    const float* x = (const float*)d_in[0];
    float* out = (float*)d_out;
    int* part = (int*)d_ws;  // NBLK * 64 ints = 64 KB

    rips_pair<<<NBLK, NTHR, 0, stream>>>(x, part);
    rips_reduce<<<1, RTHR, 0, stream>>>(part, out);
}